// Round 1
// baseline (946.091 us; speedup 1.0000x reference)
//
#include <hip/hip_runtime.h>

// ============================================================================
// ShiftedWindowAttention fused pipeline (fp32 compute, bf16 intermediates).
//
// Shapes: B=16, H=W=64, C=256, NH=8, HD=32, window 8x8 (N=64), shift 4,
// nW=64 windows/batch -> 1024 windows, 65536 token rows.
//
// Pipeline (all on `stream`):
//   memset stats -> qstats -> finalize(q) -> gemm(k)->klin(bf16 ws)
//   -> kstats(klin) -> finalize(k) -> gemm(v_scale)->vlin -> attn(branch0)
//   -> gemm(v_shift)->vlin -> attn(branch1)
//
// ws layout (floats):
//   [0,4096)qsum [4096,8192)qss [8192,12288)ksum [12288,16384)kss
//   [16384..)qA qB kA kB (4096 each)
//   klin: u16 at float-offset 32768 (16.7M u16 = 33.5MB)
//   vlin: u16 after klin (33.5MB)          total ~64.1 MiB required.
// ============================================================================

typedef unsigned short u16;

__device__ __forceinline__ float b2f(u16 u) {
  return __uint_as_float(((unsigned)u) << 16);
}
__device__ __forceinline__ u16 f2b(float f) {
  unsigned x = __float_as_uint(f);
  unsigned r = x + 0x7fffu + ((x >> 16) & 1u);
  return (u16)(r >> 16);
}
__device__ __forceinline__ float dot4acc(float acc, const float4& a, const float4& b) {
  acc = fmaf(a.x, b.x, acc);
  acc = fmaf(a.y, b.y, acc);
  acc = fmaf(a.z, b.z, acc);
  acc = fmaf(a.w, b.w, acc);
  return acc;
}

// ---------------------------------------------------------------------------
// Per-(b,c) sum / sumsq over the 4096 spatial positions. Layout is
// [b][4096][256] for both the raw f32 input and the bf16 klin buffer.
// grid = B*16 blocks (16 position-chunks of 256), 256 threads = channels.
// ---------------------------------------------------------------------------
__global__ __launch_bounds__(256) void stats_f32(const float* __restrict__ src,
                                                 float* __restrict__ osum,
                                                 float* __restrict__ oss) {
  const int blk = blockIdx.x;
  const int b = blk >> 4;
  const int p0 = (blk & 15) << 8;
  const int c = threadIdx.x;
  const float* p = src + (((size_t)b << 12) + p0) * 256 + c;
  float s = 0.f, ss = 0.f;
  for (int i = 0; i < 256; ++i) {
    float v = p[(size_t)i * 256];
    s += v;
    ss = fmaf(v, v, ss);
  }
  atomicAdd(&osum[(b << 8) + c], s);
  atomicAdd(&oss[(b << 8) + c], ss);
}

__global__ __launch_bounds__(256) void stats_b16(const u16* __restrict__ src,
                                                 float* __restrict__ osum,
                                                 float* __restrict__ oss) {
  const int blk = blockIdx.x;
  const int b = blk >> 4;
  const int p0 = (blk & 15) << 8;
  const int c = threadIdx.x;
  const u16* p = src + (((size_t)b << 12) + p0) * 256 + c;
  float s = 0.f, ss = 0.f;
  for (int i = 0; i < 256; ++i) {
    float v = b2f(p[(size_t)i * 256]);
    s += v;
    ss = fmaf(v, v, ss);
  }
  atomicAdd(&osum[(b << 8) + c], s);
  atomicAdd(&oss[(b << 8) + c], ss);
}

// A = rsqrt(var+eps)*scale ; B = -mean*A   (biased var, eps=1e-5)
__global__ void finalize_stats(const float* __restrict__ sum,
                               const float* __restrict__ ss,
                               float* __restrict__ A, float* __restrict__ Bo,
                               float scale) {
  const int i = blockIdx.x * 256 + threadIdx.x;  // 4096 entries
  float m = sum[i] * (1.f / 4096.f);
  float v = ss[i] * (1.f / 4096.f) - m * m;
  float a = rsqrtf(v + 1e-5f) * scale;
  A[i] = a;
  Bo[i] = -m * a;
}

// ---------------------------------------------------------------------------
// Gather-fused linear: dst[row,c] = sum_c' srcwin[row,c'] * W[c,c'] + bias[c]
// row -> (b, window, token) -> rolled source coords (+4 mod 64).
// 64x64 output tile per block, K-chunks of 64, 4x4 register tile / thread.
// dst stored bf16.
// ---------------------------------------------------------------------------
__global__ __launch_bounds__(256) void gemm_win(const float* __restrict__ src,
                                                const float* __restrict__ W,
                                                const float* __restrict__ bias,
                                                u16* __restrict__ dst) {
  __shared__ float A_s[64][68];
  __shared__ float B_s[64][68];
  const int t = threadIdx.x;
  const int r0 = (blockIdx.x >> 2) << 6;
  const int c0 = (blockIdx.x & 3) << 6;

  // staging assignment: 4 threads per row, 16 k-values each
  const int srow = t >> 2;
  const int sk0 = (t & 3) << 4;

  const int rg = r0 + srow;
  const int bb = rg >> 12;
  const int rr = rg & 4095;
  const int wi = rr >> 6;
  const int nn = rr & 63;
  const int hs = ((wi >> 3) << 3) + (nn >> 3);
  const int wsq = ((wi & 7) << 3) + (nn & 7);
  const size_t abase =
      (((size_t)((bb << 6) | ((hs + 4) & 63)) << 6) | ((wsq + 4) & 63)) << 8;
  const size_t wbase = (size_t)(c0 + srow) << 8;

  const int tx = t & 15, ty = t >> 4;
  float acc[4][4];
#pragma unroll
  for (int i = 0; i < 4; ++i)
#pragma unroll
    for (int j = 0; j < 4; ++j) acc[i][j] = 0.f;

  for (int kk = 0; kk < 256; kk += 64) {
    __syncthreads();
#pragma unroll
    for (int u = 0; u < 16; u += 4) {
      *reinterpret_cast<float4*>(&A_s[srow][sk0 + u]) =
          *reinterpret_cast<const float4*>(src + abase + kk + sk0 + u);
      *reinterpret_cast<float4*>(&B_s[srow][sk0 + u]) =
          *reinterpret_cast<const float4*>(W + wbase + kk + sk0 + u);
    }
    __syncthreads();
#pragma unroll
    for (int k0 = 0; k0 < 64; k0 += 4) {
      float4 av[4], bv[4];
#pragma unroll
      for (int i = 0; i < 4; ++i) {
        av[i] = *reinterpret_cast<const float4*>(&A_s[ty + (i << 4)][k0]);
        bv[i] = *reinterpret_cast<const float4*>(&B_s[tx + (i << 4)][k0]);
      }
#pragma unroll
      for (int i = 0; i < 4; ++i)
#pragma unroll
        for (int j = 0; j < 4; ++j) acc[i][j] = dot4acc(acc[i][j], av[i], bv[j]);
    }
  }
#pragma unroll
  for (int i = 0; i < 4; ++i) {
    const size_t rb = (size_t)(r0 + ty + (i << 4)) << 8;
#pragma unroll
    for (int j = 0; j < 4; ++j) {
      const int c = c0 + tx + (j << 4);
      dst[rb + c] = f2b(acc[i][j] + bias[c]);
    }
  }
}

// ---------------------------------------------------------------------------
// Window attention + fused v-linear-consumption + proj + reverse shift.
// One block per window (1024 blocks), 256 threads.
// Per head: stage q_h (normalized*HD^-.5) & k_h (normalized) -> S in regs
// (4 threads/row) + rpb + inline mask -> quad-shuffle softmax -> P(bf16 LDS)
// -> X = P@V -> proj accumulated into 64 register accumulators.
// ---------------------------------------------------------------------------
__global__ __launch_bounds__(256) void attn_win(
    const float* __restrict__ qsrc, const float* __restrict__ qA_,
    const float* __restrict__ qB_, const u16* __restrict__ klin,
    const float* __restrict__ kA_, const float* __restrict__ kB_,
    const u16* __restrict__ vlin, const float* __restrict__ rpb,
    const float* __restrict__ pW, const float* __restrict__ pbias,
    float* __restrict__ outp) {
  __shared__ float bufA[64][36];  // q_h, later v_h
  __shared__ float bufB[64][36];  // k_h, later X_h
  __shared__ u16 Pl[64][66];      // softmax(P) bf16
  __shared__ float WpT[32][260];  // proj weights, transposed slice [d][o]

  const int t = threadIdx.x;
  const int win = blockIdx.x;
  const int b = win >> 6;
  const int wIdx = win & 63;
  const int wh = wIdx >> 3, ww = wIdx & 7;
  const int rowbase = win << 6;

  const int n = t >> 2;   // attention row owned in S/X phases
  const int q4 = t & 3;   // quad id
  const int d0 = q4 << 3; // 8-channel slice

  const int hs = (wh << 3) + (n >> 3);
  const int wsc = (ww << 3) + (n & 7);
  const size_t gpos =
      (((size_t)((b << 6) | ((hs + 4) & 63)) << 6) | ((wsc + 4) & 63)) << 8;
  const int labn = ((hs < 56) ? 0 : ((hs < 60) ? 1 : 2)) * 3 +
                   ((wsc < 56) ? 0 : ((wsc < 60) ? 1 : 2));

  const int pa = t >> 4;  // proj: rows pa, pa+16, pa+32, pa+48
  const int pc = t & 15;  // proj: col chunks k*64 + pc*4

  const size_t krow = ((size_t)(rowbase + n)) << 8;

  float Y[4][16];
#pragma unroll
  for (int r = 0; r < 4; ++r)
#pragma unroll
    for (int u = 0; u < 16; ++u) Y[r][u] = 0.f;

  for (int h = 0; h < 8; ++h) {
    const int c0 = (h << 5) + d0;
    __syncthreads();
    // ---- stage q (norm+scale) and k (norm) for this head ----
    {
      const float* qp = qsrc + gpos + c0;
      const u16* kp = klin + krow + c0;
#pragma unroll
      for (int u = 0; u < 8; ++u) {
        bufA[n][d0 + u] = fmaf(qp[u], qA_[(b << 8) + c0 + u], qB_[(b << 8) + c0 + u]);
        bufB[n][d0 + u] = fmaf(b2f(kp[u]), kA_[(b << 8) + c0 + u], kB_[(b << 8) + c0 + u]);
      }
    }
    // ---- stage transposed proj-weight slice for this head ----
    {
      const float* wp = pW + (size_t)t * 256 + (h << 5);
#pragma unroll
      for (int u = 0; u < 32; u += 4) {
        float4 w = *reinterpret_cast<const float4*>(wp + u);
        WpT[u + 0][t] = w.x;
        WpT[u + 1][t] = w.y;
        WpT[u + 2][t] = w.z;
        WpT[u + 3][t] = w.w;
      }
    }
    __syncthreads();

    // ---- S = q.k^T + rpb + mask, softmax in registers ----
    float qreg[32];
#pragma unroll
    for (int u = 0; u < 32; u += 4)
      *reinterpret_cast<float4*>(&qreg[u]) =
          *reinterpret_cast<const float4*>(&bufA[n][u]);

    float p[16];
    const float* rpbrow = rpb + (h << 12) + (n << 6);
#pragma unroll
    for (int mm = 0; mm < 16; ++mm) {
      const int m = (mm << 2) + q4;
      const int mhs = (wh << 3) + (m >> 3);
      const int mws = (ww << 3) + (m & 7);
      const int labm = ((mhs < 56) ? 0 : ((mhs < 60) ? 1 : 2)) * 3 +
                       ((mws < 56) ? 0 : ((mws < 60) ? 1 : 2));
      float acc = rpbrow[m] + ((labm == labn) ? 0.f : -100.f);
#pragma unroll
      for (int dd = 0; dd < 32; dd += 4) {
        float4 kv = *reinterpret_cast<const float4*>(&bufB[m][dd]);
        acc = fmaf(qreg[dd + 0], kv.x, acc);
        acc = fmaf(qreg[dd + 1], kv.y, acc);
        acc = fmaf(qreg[dd + 2], kv.z, acc);
        acc = fmaf(qreg[dd + 3], kv.w, acc);
      }
      p[mm] = acc;
    }
    float mx = p[0];
#pragma unroll
    for (int mm = 1; mm < 16; ++mm) mx = fmaxf(mx, p[mm]);
    mx = fmaxf(mx, __shfl_xor(mx, 1));
    mx = fmaxf(mx, __shfl_xor(mx, 2));
    float ssum = 0.f;
#pragma unroll
    for (int mm = 0; mm < 16; ++mm) {
      p[mm] = __expf(p[mm] - mx);
      ssum += p[mm];
    }
    ssum += __shfl_xor(ssum, 1);
    ssum += __shfl_xor(ssum, 2);
    const float inv = 1.f / ssum;
#pragma unroll
    for (int mm = 0; mm < 16; ++mm) Pl[n][(mm << 2) + q4] = f2b(p[mm] * inv);

    __syncthreads();
    // ---- stage v_h (overwrites q_h) ----
    {
      const u16* vp = vlin + krow + c0;
#pragma unroll
      for (int u = 0; u < 8; ++u) bufA[n][d0 + u] = b2f(vp[u]);
    }
    __syncthreads();

    // ---- X = P @ V (row n, channel slice d0..d0+7) ----
    float X[8];
#pragma unroll
    for (int u = 0; u < 8; ++u) X[u] = 0.f;
#pragma unroll 8
    for (int m = 0; m < 64; ++m) {
      const float pv = b2f(Pl[n][m]);
      float4 v0 = *reinterpret_cast<const float4*>(&bufA[m][d0]);
      float4 v1 = *reinterpret_cast<const float4*>(&bufA[m][d0 + 4]);
      X[0] = fmaf(pv, v0.x, X[0]);
      X[1] = fmaf(pv, v0.y, X[1]);
      X[2] = fmaf(pv, v0.z, X[2]);
      X[3] = fmaf(pv, v0.w, X[3]);
      X[4] = fmaf(pv, v1.x, X[4]);
      X[5] = fmaf(pv, v1.y, X[5]);
      X[6] = fmaf(pv, v1.z, X[6]);
      X[7] = fmaf(pv, v1.w, X[7]);
    }
    // write X into bufB (k_h dead since the post-softmax barrier)
    *reinterpret_cast<float4*>(&bufB[n][d0]) = make_float4(X[0], X[1], X[2], X[3]);
    *reinterpret_cast<float4*>(&bufB[n][d0 + 4]) = make_float4(X[4], X[5], X[6], X[7]);
    __syncthreads();

    // ---- proj accumulate: Y[r][k*4+u] += X[row][d] * WpT[d][k*64+pc*4+u] ----
#pragma unroll 8
    for (int d = 0; d < 32; ++d) {
      float x0 = bufB[pa][d];
      float x1 = bufB[pa + 16][d];
      float x2 = bufB[pa + 32][d];
      float x3 = bufB[pa + 48][d];
#pragma unroll
      for (int k = 0; k < 4; ++k) {
        float4 w = *reinterpret_cast<const float4*>(&WpT[d][(k << 6) + (pc << 2)]);
        Y[0][k * 4 + 0] = fmaf(x0, w.x, Y[0][k * 4 + 0]);
        Y[0][k * 4 + 1] = fmaf(x0, w.y, Y[0][k * 4 + 1]);
        Y[0][k * 4 + 2] = fmaf(x0, w.z, Y[0][k * 4 + 2]);
        Y[0][k * 4 + 3] = fmaf(x0, w.w, Y[0][k * 4 + 3]);
        Y[1][k * 4 + 0] = fmaf(x1, w.x, Y[1][k * 4 + 0]);
        Y[1][k * 4 + 1] = fmaf(x1, w.y, Y[1][k * 4 + 1]);
        Y[1][k * 4 + 2] = fmaf(x1, w.z, Y[1][k * 4 + 2]);
        Y[1][k * 4 + 3] = fmaf(x1, w.w, Y[1][k * 4 + 3]);
        Y[2][k * 4 + 0] = fmaf(x2, w.x, Y[2][k * 4 + 0]);
        Y[2][k * 4 + 1] = fmaf(x2, w.y, Y[2][k * 4 + 1]);
        Y[2][k * 4 + 2] = fmaf(x2, w.z, Y[2][k * 4 + 2]);
        Y[2][k * 4 + 3] = fmaf(x2, w.w, Y[2][k * 4 + 3]);
        Y[3][k * 4 + 0] = fmaf(x3, w.x, Y[3][k * 4 + 0]);
        Y[3][k * 4 + 1] = fmaf(x3, w.y, Y[3][k * 4 + 1]);
        Y[3][k * 4 + 2] = fmaf(x3, w.z, Y[3][k * 4 + 2]);
        Y[3][k * 4 + 3] = fmaf(x3, w.w, Y[3][k * 4 + 3]);
      }
    }
  }  // heads

  // ---- epilogue: +bias, reverse cyclic shift scatter ----
#pragma unroll
  for (int r = 0; r < 4; ++r) {
    const int row = pa + (r << 4);
    const int rhs = (wh << 3) + (row >> 3);
    const int rws = (ww << 3) + (row & 7);
    float* op = outp + ((((size_t)((b << 6) | ((rhs + 4) & 63)) << 6) |
                         ((rws + 4) & 63))
                        << 8);
#pragma unroll
    for (int k = 0; k < 4; ++k) {
      const int o0 = (k << 6) + (pc << 2);
      float4 pbv = *reinterpret_cast<const float4*>(pbias + o0);
      float4 v;
      v.x = Y[r][k * 4 + 0] + pbv.x;
      v.y = Y[r][k * 4 + 1] + pbv.y;
      v.z = Y[r][k * 4 + 2] + pbv.z;
      v.w = Y[r][k * 4 + 3] + pbv.w;
      *reinterpret_cast<float4*>(op + o0) = v;
    }
  }
}

// ---------------------------------------------------------------------------
extern "C" void kernel_launch(void* const* d_in, const int* in_sizes, int n_in,
                              void* d_out, int out_size, void* d_ws,
                              size_t ws_size, hipStream_t stream) {
  (void)in_sizes; (void)n_in; (void)out_size; (void)ws_size;
  const float* q   = (const float*)d_in[0];
  const float* k   = (const float*)d_in[1];
  const float* vs  = (const float*)d_in[2];
  const float* vsh = (const float*)d_in[3];
  const float* kW  = (const float*)d_in[4];
  const float* kb  = (const float*)d_in[5];
  const float* vWs = (const float*)d_in[6];
  const float* vbs = (const float*)d_in[7];
  const float* vWh = (const float*)d_in[8];
  const float* vbh = (const float*)d_in[9];
  const float* pW  = (const float*)d_in[10];
  const float* pb  = (const float*)d_in[11];
  const float* rpb = (const float*)d_in[12];
  float* out = (float*)d_out;

  float* f = (float*)d_ws;
  float* qsum = f;
  float* qss  = f + 4096;
  float* ksum = f + 8192;
  float* kss  = f + 12288;
  float* qA = f + 16384;
  float* qB = f + 20480;
  float* kA = f + 24576;
  float* kB = f + 28672;
  u16* klin = (u16*)(f + 32768);
  u16* vlin = klin + 16777216;

  hipMemsetAsync(f, 0, 16384 * sizeof(float), stream);
  stats_f32<<<256, 256, 0, stream>>>(q, qsum, qss);
  finalize_stats<<<16, 256, 0, stream>>>(qsum, qss, qA, qB,
                                         0.17677669529663687f);  // 1/sqrt(32)
  gemm_win<<<4096, 256, 0, stream>>>(k, kW, kb, klin);
  stats_b16<<<256, 256, 0, stream>>>(klin, ksum, kss);
  finalize_stats<<<16, 256, 0, stream>>>(ksum, kss, kA, kB, 1.0f);

  gemm_win<<<4096, 256, 0, stream>>>(vs, vWs, vbs, vlin);
  attn_win<<<1024, 256, 0, stream>>>(q, qA, qB, klin, kA, kB, vlin, rpb, pW,
                                     pb, out);
  gemm_win<<<4096, 256, 0, stream>>>(vsh, vWh, vbh, vlin);
  attn_win<<<1024, 256, 0, stream>>>(q, qA, qB, klin, kA, kB, vlin, rpb, pW,
                                     pb, out + 16777216);
}

// Round 2
// 337.245 us; speedup vs baseline: 2.8054x; 2.8054x over previous
//
#include <hip/hip_runtime.h>

// ============================================================================
// ShiftedWindowAttention — bf16 MFMA pipeline.
// B=16,H=W=64,C=256,NH=8,HD=32, win 8x8 (N=64), shift 4 -> 1024 windows.
//
// stats(q) -> finalize -> rpbm_prep -> gemm<0>(k)->klin -> stats(klin) ->
// finalize -> gemm<1>(v_s)->vt[0] -> gemm<1>(v_sh)->vt[1] ->
// attn (QK+softmax once, PV both branches) -> X_s (in d_out hi), X_sh (ws)
// -> proj(X_s)->out_lo -> proj(X_sh)->out_hi.
//
// ws floats: [0,16384) stats; [16384,32768) qA qB kA kB;
// [32768,163840) rpbm (4 var x 8 h x 64 lane x 64);
// klin u16 @f163840 (33.5MB); vt u16 @f8552448 (67MB, [br][win*256+d][64]);
// xsh u16 @f25329664 (33.5MB). Total ~135MB.
// ============================================================================

typedef unsigned short u16;
typedef unsigned int u32;
typedef __attribute__((ext_vector_type(8))) short bf16x8;   // 8 bf16 = 4 VGPR
typedef __attribute__((ext_vector_type(4))) float f32x4;

__device__ __forceinline__ float b2f(u16 u) {
  return __uint_as_float(((u32)u) << 16);
}
__device__ __forceinline__ u16 f2b(float f) {
  u32 x = __float_as_uint(f);
  return (u16)((x + 0x7fffu + ((x >> 16) & 1u)) >> 16);
}
__device__ __forceinline__ u32 pk2(float a, float b) {
  return (u32)f2b(a) | ((u32)f2b(b) << 16);
}

// ---------------------------------------------------------------------------
// stats kernels (per (b,c) sum/sumsq over 4096 positions)
// ---------------------------------------------------------------------------
__global__ __launch_bounds__(256) void stats_f32(const float* __restrict__ src,
                                                 float* __restrict__ osum,
                                                 float* __restrict__ oss) {
  const int blk = blockIdx.x;
  const int b = blk >> 4;
  const int p0 = (blk & 15) << 8;
  const int c = threadIdx.x;
  const float* p = src + (((size_t)b << 12) + p0) * 256 + c;
  float s = 0.f, ss = 0.f;
  for (int i = 0; i < 256; ++i) {
    float v = p[(size_t)i * 256];
    s += v;
    ss = fmaf(v, v, ss);
  }
  atomicAdd(&osum[(b << 8) + c], s);
  atomicAdd(&oss[(b << 8) + c], ss);
}

__global__ __launch_bounds__(256) void stats_b16(const u16* __restrict__ src,
                                                 float* __restrict__ osum,
                                                 float* __restrict__ oss) {
  const int blk = blockIdx.x;
  const int b = blk >> 4;
  const int p0 = (blk & 15) << 8;
  const int c = threadIdx.x;
  const u16* p = src + (((size_t)b << 12) + p0) * 256 + c;
  float s = 0.f, ss = 0.f;
  for (int i = 0; i < 256; ++i) {
    float v = b2f(p[(size_t)i * 256]);
    s += v;
    ss = fmaf(v, v, ss);
  }
  atomicAdd(&osum[(b << 8) + c], s);
  atomicAdd(&oss[(b << 8) + c], ss);
}

__global__ void finalize_stats(const float* __restrict__ sum,
                               const float* __restrict__ ss,
                               float* __restrict__ A, float* __restrict__ Bo,
                               float scale) {
  const int i = blockIdx.x * 256 + threadIdx.x;
  float m = sum[i] * (1.f / 4096.f);
  float v = ss[i] * (1.f / 4096.f) - m * m;
  float a = rsqrtf(v + 1e-5f) * scale;
  A[i] = a;
  Bo[i] = -m * a;
}

// ---------------------------------------------------------------------------
// rpb + mask fused, laid out in MFMA D-fragment order:
// rpbm[var][h][lane][cf*16 + rf*4 + r] ; n = 16rf+4(lane>>4)+r, m = (lane&15)+16cf
// ---------------------------------------------------------------------------
__global__ __launch_bounds__(256) void rpbm_prep(const float* __restrict__ rpb,
                                                 float* __restrict__ rpbm) {
  const int idx = blockIdx.x * 256 + threadIdx.x;  // 131072
  const int t = idx & 63;
  const int lane = (idx >> 6) & 63;
  const int h = (idx >> 12) & 7;
  const int var = idx >> 15;
  const int cf = t >> 4, rf = (t >> 2) & 3, r = t & 3;
  const int n = ((lane >> 4) << 2) + r + (rf << 4);
  const int m = (lane & 15) + (cf << 4);
  const int vh = var >> 1, vw = var & 1;
  const int ln = (vh ? (1 + ((n >> 3) >= 4)) : 0) * 3 + (vw ? (1 + ((n & 7) >= 4)) : 0);
  const int lm = (vh ? (1 + ((m >> 3) >= 4)) : 0) * 3 + (vw ? (1 + ((m & 7) >= 4)) : 0);
  rpbm[idx] = rpb[(h << 12) + (n << 6) + m] + ((ln == lm) ? 0.f : -100.f);
}

// ---------------------------------------------------------------------------
// MFMA linear: dst = gather_window_shift(src) @ W^T + bias, stored bf16.
// MODE 0: row-major [row][256] (klin). MODE 1: per-window transposed
// vt[(win*256+col)*64 + token] with packed 8B stores.
// BM=128 BN=128 BK=64, 256 thr (2x2 waves of 64x64).
// ---------------------------------------------------------------------------
template <int MODE>
__global__ __launch_bounds__(256) void gemm_lin(const float* __restrict__ src,
                                                const float* __restrict__ W,
                                                const float* __restrict__ bias,
                                                u16* __restrict__ dst) {
  __shared__ u16 A_s[128][72];
  __shared__ u16 B_s[128][72];
  const int t = threadIdx.x;
  const int r0 = blockIdx.x << 7;
  const int c0 = blockIdx.y << 7;
  const int srow = t >> 1;
  const int kh = (t & 1) << 5;

  const int rg = r0 + srow;
  const int bb = rg >> 12;
  const int rr = rg & 4095;
  const int wi = rr >> 6;
  const int nn = rr & 63;
  const int hs = ((wi >> 3) << 3) + (nn >> 3);
  const int wsq = ((wi & 7) << 3) + (nn & 7);
  const size_t abase =
      (((size_t)((bb << 6) | ((hs + 4) & 63)) << 6) | ((wsq + 4) & 63)) << 8;
  const size_t wbase = (size_t)(c0 + srow) << 8;

  const int wid = t >> 6, l = t & 63, u = l & 15, g = l >> 4;
  const int wr = wid >> 1, wc = wid & 1;

  f32x4 acc[4][4];
#pragma unroll
  for (int i = 0; i < 4; ++i)
#pragma unroll
    for (int j = 0; j < 4; ++j) acc[i][j] = {0.f, 0.f, 0.f, 0.f};

  for (int kk = 0; kk < 256; kk += 64) {
    __syncthreads();
    {
      const float* ap = src + abase + kk + kh;
      const float* bp = W + wbase + kk + kh;
#pragma unroll
      for (int q4 = 0; q4 < 4; ++q4) {
        float4 v0 = *(const float4*)(ap + (q4 << 3));
        float4 v1 = *(const float4*)(ap + (q4 << 3) + 4);
        uint4 w;
        w.x = pk2(v0.x, v0.y); w.y = pk2(v0.z, v0.w);
        w.z = pk2(v1.x, v1.y); w.w = pk2(v1.z, v1.w);
        *(uint4*)&A_s[srow][kh + (q4 << 3)] = w;
        float4 u0 = *(const float4*)(bp + (q4 << 3));
        float4 u1 = *(const float4*)(bp + (q4 << 3) + 4);
        uint4 x;
        x.x = pk2(u0.x, u0.y); x.y = pk2(u0.z, u0.w);
        x.z = pk2(u1.x, u1.y); x.w = pk2(u1.z, u1.w);
        *(uint4*)&B_s[srow][kh + (q4 << 3)] = x;
      }
    }
    __syncthreads();
#pragma unroll
    for (int ks = 0; ks < 2; ++ks) {
      bf16x8 a[4], bfr[4];
#pragma unroll
      for (int rf = 0; rf < 4; ++rf)
        a[rf] = *(const bf16x8*)&A_s[(wr << 6) + (rf << 4) + u][(ks << 5) + (g << 3)];
#pragma unroll
      for (int cf = 0; cf < 4; ++cf)
        bfr[cf] = *(const bf16x8*)&B_s[(wc << 6) + (cf << 4) + u][(ks << 5) + (g << 3)];
#pragma unroll
      for (int rf = 0; rf < 4; ++rf)
#pragma unroll
        for (int cf = 0; cf < 4; ++cf)
          acc[rf][cf] = __builtin_amdgcn_mfma_f32_16x16x32_bf16(a[rf], bfr[cf],
                                                                acc[rf][cf], 0, 0, 0);
    }
  }

#pragma unroll
  for (int cf = 0; cf < 4; ++cf) {
    const int col = c0 + (wc << 6) + (cf << 4) + u;
    const float bv = bias[col];
#pragma unroll
    for (int rf = 0; rf < 4; ++rf) {
      const int row0 = r0 + (wr << 6) + (rf << 4) + (g << 2);
      if (MODE == 0) {
#pragma unroll
        for (int r = 0; r < 4; ++r)
          dst[((size_t)(row0 + r) << 8) + col] = f2b(acc[rf][cf][r] + bv);
      } else {
        const int win = row0 >> 6;
        const int t0 = row0 & 63;
        u32 w0 = pk2(acc[rf][cf][0] + bv, acc[rf][cf][1] + bv);
        u32 w1 = pk2(acc[rf][cf][2] + bv, acc[rf][cf][3] + bv);
        *(uint2*)(dst + (((size_t)(win << 8) + col) << 6) + t0) = make_uint2(w0, w1);
      }
    }
  }
}

// ---------------------------------------------------------------------------
// Attention: one wave per (window, head). QK^T MFMA -> fragment softmax ->
// P bf16 LDS -> PV MFMA for both branches (V direct from global vt) ->
// X stored bf16 [row][256]. Blocks of 4 waves (same window, heads share L1).
// ---------------------------------------------------------------------------
__global__ __launch_bounds__(256) void attn_mfma(
    const float* __restrict__ qsrc, const float* __restrict__ qA_,
    const float* __restrict__ qB_, const u16* __restrict__ klin,
    const float* __restrict__ kA_, const float* __restrict__ kB_,
    const u16* __restrict__ vt, const float* __restrict__ rpbm,
    u16* __restrict__ xs, u16* __restrict__ xsh) {
  __shared__ u16 P[4][64][72];
  const int tid = threadIdx.x;
  const int wid = tid >> 6;
  const int l = tid & 63;
  const int u = l & 15;
  const int g = l >> 4;
  const int task = blockIdx.x * 4 + wid;
  const int win = task >> 3;
  const int h = task & 7;
  const int b = win >> 6;
  const int wIdx = win & 63;
  const int wh = wIdx >> 3, ww = wIdx & 7;
  const int var = ((wh == 7) ? 2 : 0) | ((ww == 7) ? 1 : 0);
  const int coff = (h << 5) + (g << 3);

  float qav[8], qbv[8], kav[8], kbv[8];
  {
    const int o = (b << 8) + coff;
    float4 a0 = *(const float4*)(qA_ + o), a1 = *(const float4*)(qA_ + o + 4);
    float4 b0 = *(const float4*)(qB_ + o), b1 = *(const float4*)(qB_ + o + 4);
    float4 c0v = *(const float4*)(kA_ + o), c1 = *(const float4*)(kA_ + o + 4);
    float4 d0v = *(const float4*)(kB_ + o), d1 = *(const float4*)(kB_ + o + 4);
    qav[0]=a0.x;qav[1]=a0.y;qav[2]=a0.z;qav[3]=a0.w;qav[4]=a1.x;qav[5]=a1.y;qav[6]=a1.z;qav[7]=a1.w;
    qbv[0]=b0.x;qbv[1]=b0.y;qbv[2]=b0.z;qbv[3]=b0.w;qbv[4]=b1.x;qbv[5]=b1.y;qbv[6]=b1.z;qbv[7]=b1.w;
    kav[0]=c0v.x;kav[1]=c0v.y;kav[2]=c0v.z;kav[3]=c0v.w;kav[4]=c1.x;kav[5]=c1.y;kav[6]=c1.z;kav[7]=c1.w;
    kbv[0]=d0v.x;kbv[1]=d0v.y;kbv[2]=d0v.z;kbv[3]=d0v.w;kbv[4]=d1.x;kbv[5]=d1.y;kbv[6]=d1.z;kbv[7]=d1.w;
  }

  // q fragments (gathered + normalized + scaled)
  bf16x8 qf[4];
#pragma unroll
  for (int rf = 0; rf < 4; ++rf) {
    const int n = (rf << 4) + u;
    const int nhs = (wh << 3) + (n >> 3);
    const int nws = (ww << 3) + (n & 7);
    const float* qp = qsrc +
        ((((size_t)((b << 6) | ((nhs + 4) & 63)) << 6) | ((nws + 4) & 63)) << 8) + coff;
    float4 v0 = *(const float4*)qp;
    float4 v1 = *(const float4*)(qp + 4);
    float qv[8] = {v0.x, v0.y, v0.z, v0.w, v1.x, v1.y, v1.z, v1.w};
#pragma unroll
    for (int j = 0; j < 8; ++j) qf[rf][j] = (short)f2b(fmaf(qv[j], qav[j], qbv[j]));
  }

  // k fragments (bf16 + affine normalization)
  bf16x8 kf[4];
#pragma unroll
  for (int cf = 0; cf < 4; ++cf) {
    const int m = (cf << 4) + u;
    const u16* kp = klin + (((size_t)(win << 6) + m) << 8) + coff;
    union { uint4 v; u16 s[8]; } raw;
    raw.v = *(const uint4*)kp;
#pragma unroll
    for (int j = 0; j < 8; ++j)
      kf[cf][j] = (short)f2b(fmaf(b2f(raw.s[j]), kav[j], kbv[j]));
  }

  // S = q k^T
  f32x4 s[4][4];
  const f32x4 z4 = {0.f, 0.f, 0.f, 0.f};
#pragma unroll
  for (int rf = 0; rf < 4; ++rf)
#pragma unroll
    for (int cf = 0; cf < 4; ++cf)
      s[rf][cf] = __builtin_amdgcn_mfma_f32_16x16x32_bf16(qf[rf], kf[cf], z4, 0, 0, 0);

  // + rpb + mask (pre-fused, fragment order)
  const float* rb = rpbm + ((((var << 3) + h) << 6) + l) * 64;
#pragma unroll
  for (int cf = 0; cf < 4; ++cf)
#pragma unroll
    for (int rf = 0; rf < 4; ++rf) {
      float4 bv = *(const float4*)(rb + (cf << 4) + (rf << 2));
      s[rf][cf][0] += bv.x; s[rf][cf][1] += bv.y;
      s[rf][cf][2] += bv.z; s[rf][cf][3] += bv.w;
    }

  // softmax over m (4 col-frags x 16 lanes)
  f32x4 inv[4];
#pragma unroll
  for (int rf = 0; rf < 4; ++rf) {
#pragma unroll
    for (int r = 0; r < 4; ++r) {
      float m0 = fmaxf(fmaxf(s[rf][0][r], s[rf][1][r]),
                       fmaxf(s[rf][2][r], s[rf][3][r]));
      m0 = fmaxf(m0, __shfl_xor(m0, 1));
      m0 = fmaxf(m0, __shfl_xor(m0, 2));
      m0 = fmaxf(m0, __shfl_xor(m0, 4));
      m0 = fmaxf(m0, __shfl_xor(m0, 8));
      float t0 = 0.f;
#pragma unroll
      for (int cf = 0; cf < 4; ++cf) {
        s[rf][cf][r] = __expf(s[rf][cf][r] - m0);
        t0 += s[rf][cf][r];
      }
      t0 += __shfl_xor(t0, 1);
      t0 += __shfl_xor(t0, 2);
      t0 += __shfl_xor(t0, 4);
      t0 += __shfl_xor(t0, 8);
      inv[rf][r] = 1.f / t0;
    }
  }

  // P -> LDS (row-major [n][m], bf16)
#pragma unroll
  for (int rf = 0; rf < 4; ++rf)
#pragma unroll
    for (int r = 0; r < 4; ++r) {
      const int n = (rf << 4) + (g << 2) + r;
#pragma unroll
      for (int cf = 0; cf < 4; ++cf)
        P[wid][n][(cf << 4) + u] = f2b(s[rf][cf][r] * inv[rf][r]);
    }

  // PV for both branches: Xt[d][n] = sum_m Vt[d][m] P[n][m]
#pragma unroll
  for (int br = 0; br < 2; ++br) {
    const u16* vb = vt + br * 16777216 + (((win << 8) + (h << 5) + u) << 6);
    bf16x8 vf[2][2];
#pragma unroll
    for (int df = 0; df < 2; ++df)
#pragma unroll
      for (int ks = 0; ks < 2; ++ks)
        vf[df][ks] = *(const bf16x8*)(vb + (df << 10) + (ks << 5) + (g << 3));
    f32x4 xt[2][4];
#pragma unroll
    for (int df = 0; df < 2; ++df)
#pragma unroll
      for (int cf = 0; cf < 4; ++cf) xt[df][cf] = z4;
#pragma unroll
    for (int cf = 0; cf < 4; ++cf)
#pragma unroll
      for (int ks = 0; ks < 2; ++ks) {
        bf16x8 pf = *(const bf16x8*)&P[wid][(cf << 4) + u][(ks << 5) + (g << 3)];
        xt[0][cf] = __builtin_amdgcn_mfma_f32_16x16x32_bf16(vf[0][ks], pf, xt[0][cf], 0, 0, 0);
        xt[1][cf] = __builtin_amdgcn_mfma_f32_16x16x32_bf16(vf[1][ks], pf, xt[1][cf], 0, 0, 0);
      }
    u16* xb = br ? xsh : xs;
#pragma unroll
    for (int df = 0; df < 2; ++df)
#pragma unroll
      for (int cf = 0; cf < 4; ++cf) {
        u32 w0 = pk2(xt[df][cf][0], xt[df][cf][1]);
        u32 w1 = pk2(xt[df][cf][2], xt[df][cf][3]);
        const size_t idx =
            (((size_t)(win << 6) + (cf << 4) + u) << 8) + (h << 5) + (df << 4) + (g << 2);
        *(uint2*)(xb + idx) = make_uint2(w0, w1);
      }
  }
}

// ---------------------------------------------------------------------------
// Proj GEMM: out = X @ pW^T + pb, fused reverse-shift scatter, f32 out.
// ---------------------------------------------------------------------------
__global__ __launch_bounds__(256) void proj_gemm(const u16* __restrict__ X,
                                                 const float* __restrict__ W,
                                                 const float* __restrict__ bias,
                                                 float* __restrict__ outp) {
  __shared__ u16 A_s[128][72];
  __shared__ u16 B_s[128][72];
  const int t = threadIdx.x;
  const int r0 = blockIdx.x << 7;
  const int c0 = blockIdx.y << 7;
  const int srow = t >> 1;
  const int kh = (t & 1) << 5;
  const size_t abase = ((size_t)(r0 + srow) << 8);
  const size_t wbase = (size_t)(c0 + srow) << 8;

  const int wid = t >> 6, l = t & 63, u = l & 15, g = l >> 4;
  const int wr = wid >> 1, wc = wid & 1;

  f32x4 acc[4][4];
#pragma unroll
  for (int i = 0; i < 4; ++i)
#pragma unroll
    for (int j = 0; j < 4; ++j) acc[i][j] = {0.f, 0.f, 0.f, 0.f};

  for (int kk = 0; kk < 256; kk += 64) {
    __syncthreads();
    {
      const uint4* xp = (const uint4*)(X + abase + kk + kh);
#pragma unroll
      for (int j = 0; j < 4; ++j) *(uint4*)&A_s[srow][kh + (j << 3)] = xp[j];
      const float* bp = W + wbase + kk + kh;
#pragma unroll
      for (int q4 = 0; q4 < 4; ++q4) {
        float4 u0 = *(const float4*)(bp + (q4 << 3));
        float4 u1 = *(const float4*)(bp + (q4 << 3) + 4);
        uint4 x;
        x.x = pk2(u0.x, u0.y); x.y = pk2(u0.z, u0.w);
        x.z = pk2(u1.x, u1.y); x.w = pk2(u1.z, u1.w);
        *(uint4*)&B_s[srow][kh + (q4 << 3)] = x;
      }
    }
    __syncthreads();
#pragma unroll
    for (int ks = 0; ks < 2; ++ks) {
      bf16x8 a[4], bfr[4];
#pragma unroll
      for (int rf = 0; rf < 4; ++rf)
        a[rf] = *(const bf16x8*)&A_s[(wr << 6) + (rf << 4) + u][(ks << 5) + (g << 3)];
#pragma unroll
      for (int cf = 0; cf < 4; ++cf)
        bfr[cf] = *(const bf16x8*)&B_s[(wc << 6) + (cf << 4) + u][(ks << 5) + (g << 3)];
#pragma unroll
      for (int rf = 0; rf < 4; ++rf)
#pragma unroll
        for (int cf = 0; cf < 4; ++cf)
          acc[rf][cf] = __builtin_amdgcn_mfma_f32_16x16x32_bf16(a[rf], bfr[cf],
                                                                acc[rf][cf], 0, 0, 0);
    }
  }

#pragma unroll
  for (int cf = 0; cf < 4; ++cf) {
    const int col = c0 + (wc << 6) + (cf << 4) + u;
    const float bv = bias[col];
#pragma unroll
    for (int rf = 0; rf < 4; ++rf) {
      const int row0 = r0 + (wr << 6) + (rf << 4) + (g << 2);
      const int win = row0 >> 6;
      const int n0 = row0 & 63;
      const int bb = win >> 6;
      const int wh = (win >> 3) & 7, ww = win & 7;
      const int nhs = (wh << 3) + (n0 >> 3);
      const int wsb = (ww << 3) + (n0 & 7);
#pragma unroll
      for (int r = 0; r < 4; ++r) {
        outp[((((size_t)((bb << 6) | ((nhs + 4) & 63)) << 6) | ((wsb + r + 4) & 63)) << 8) + col] =
            acc[rf][cf][r] + bv;
      }
    }
  }
}

// ---------------------------------------------------------------------------
extern "C" void kernel_launch(void* const* d_in, const int* in_sizes, int n_in,
                              void* d_out, int out_size, void* d_ws,
                              size_t ws_size, hipStream_t stream) {
  (void)in_sizes; (void)n_in; (void)out_size; (void)ws_size;
  const float* q   = (const float*)d_in[0];
  const float* k   = (const float*)d_in[1];
  const float* vs  = (const float*)d_in[2];
  const float* vsh = (const float*)d_in[3];
  const float* kW  = (const float*)d_in[4];
  const float* kb  = (const float*)d_in[5];
  const float* vWs = (const float*)d_in[6];
  const float* vbs = (const float*)d_in[7];
  const float* vWh = (const float*)d_in[8];
  const float* vbh = (const float*)d_in[9];
  const float* pW  = (const float*)d_in[10];
  const float* pb  = (const float*)d_in[11];
  const float* rpb = (const float*)d_in[12];
  float* out = (float*)d_out;

  float* f = (float*)d_ws;
  float* qsum = f;
  float* qss  = f + 4096;
  float* ksum = f + 8192;
  float* kss  = f + 12288;
  float* qA = f + 16384;
  float* qB = f + 20480;
  float* kA = f + 24576;
  float* kB = f + 28672;
  float* rpbm = f + 32768;                    // 131072 floats
  u16* klin = (u16*)(f + 163840);             // 16.7M u16
  u16* vt   = (u16*)(f + 8552448);            // 33.5M u16 (2 branches)
  u16* xsh  = (u16*)(f + 25329664);           // 16.7M u16
  u16* xs   = (u16*)(out + 16777216);         // parked in d_out hi half

  hipMemsetAsync(f, 0, 16384 * sizeof(float), stream);
  stats_f32<<<256, 256, 0, stream>>>(q, qsum, qss);
  finalize_stats<<<16, 256, 0, stream>>>(qsum, qss, qA, qB,
                                         0.17677669529663687f);  // 1/sqrt(32)
  rpbm_prep<<<512, 256, 0, stream>>>(rpb, rpbm);

  dim3 gg(512, 2);
  gemm_lin<0><<<gg, 256, 0, stream>>>(k, kW, kb, klin);
  stats_b16<<<256, 256, 0, stream>>>(klin, ksum, kss);
  finalize_stats<<<16, 256, 0, stream>>>(ksum, kss, kA, kB, 1.0f);

  gemm_lin<1><<<gg, 256, 0, stream>>>(vs, vWs, vbs, vt);
  gemm_lin<1><<<gg, 256, 0, stream>>>(vsh, vWh, vbh, vt + 16777216);

  attn_mfma<<<2048, 256, 0, stream>>>(q, qA, qB, klin, kA, kB, vt, rpbm, xs, xsh);

  proj_gemm<<<gg, 256, 0, stream>>>(xs, pW, pb, out);
  proj_gemm<<<gg, 256, 0, stream>>>(xsh, pW, pb, out + 16777216);
}